// Round 6
// baseline (339.397 us; speedup 1.0000x reference)
//
#include <hip/hip_runtime.h>
#include <math.h>
#include <cstdint>
#include <cstddef>

#define DI __device__ __forceinline__

typedef __bf16 bf16x8 __attribute__((ext_vector_type(8)));
typedef float f32x4 __attribute__((ext_vector_type(4)));

static constexpr int kB = 4, kS = 2048, kD = 1024;
static constexpr int kM = kB * kS;            // 8192 tokens
static constexpr float kScale = 0.03125f;     // 1/sqrt(1024)
static constexpr float kEps = 1e-5f;

DI unsigned short f2bf(float f) {
  unsigned u = __float_as_uint(f);
  u += 0x7FFFu + ((u >> 16) & 1u);   // round-to-nearest-even
  return (unsigned short)(u >> 16);
}
DI float bf2f(unsigned short h) {
  return __uint_as_float(((unsigned)h) << 16);
}

DI void gld_lds16(const void* g, void* l) {
  __builtin_amdgcn_global_load_lds(
      (__attribute__((address_space(1))) void*)(void*)g,
      (__attribute__((address_space(3))) void*)l, 16, 0, 0);
}

#define SBAR() __builtin_amdgcn_sched_barrier(0)
#define FULLBAR() do { SBAR(); __builtin_amdgcn_s_barrier(); SBAR(); } while (0)

// ------- fused cast fp32 -> bf16 (x, Wq|Wk concat, Wv, W1, W2) -------
__global__ __launch_bounds__(256) void k_cast_all(
    const float* __restrict__ x, const float* __restrict__ Wq,
    const float* __restrict__ Wk, const float* __restrict__ Wv,
    const float* __restrict__ W1, const float* __restrict__ W2,
    unsigned short* __restrict__ xb, unsigned short* __restrict__ Wqkb,
    unsigned short* __restrict__ Wvb, unsigned short* __restrict__ W1b,
    unsigned short* __restrict__ W2b) {
  const int i = blockIdx.x * 256 + threadIdx.x;     // float4 index
  const int X4 = kM * kD / 4;                       // 2,097,152
  const int W4 = kD * kD / 4;                       // 262,144
  const float* src;
  unsigned short* dst;
  int j;
  if (i < X4) { src = x; dst = xb; j = i; }
  else if (i < X4 + W4)     { src = Wq; dst = Wqkb;          j = i - X4; }
  else if (i < X4 + 2 * W4) { src = Wk; dst = Wqkb + 4 * W4; j = i - X4 - W4; }
  else if (i < X4 + 3 * W4) { src = Wv; dst = Wvb;           j = i - X4 - 2 * W4; }
  else if (i < X4 + 4 * W4) { src = W1; dst = W1b;           j = i - X4 - 3 * W4; }
  else                      { src = W2; dst = W2b;           j = i - X4 - 4 * W4; }
  float4 v = ((const float4*)src)[j];
  ushort4 o;
  o.x = f2bf(v.x); o.y = f2bf(v.y); o.z = f2bf(v.z); o.w = f2bf(v.w);
  ((ushort4*)dst)[j] = o;
}

// ================= 8-phase 256-row bf16 NT GEMM (banked for Vt/FFN) =========
// Measured: modest win over 2-phase on the 256-block single-round shapes
// (R5 vs R0: -12us for the trio). LOST on QK in every config; never launch
// with != 256 blocks.
template <int NF, int OUT_BF16, int RELU>
__global__ __launch_bounds__(512, 2) void k_gemm8p(
    const unsigned short* __restrict__ A, const unsigned short* __restrict__ B,
    void* __restrict__ Cv, const float* __restrict__ bias,
    int M, int N, int K, int lda, int ldb, int ldc,
    long sA, long sB, long sC, int cColOff) {
  constexpr int BN = NF * 64;
  constexpr int LB = BN / 128;          // gld_lds issues per thread per B half
  constexpr int VM = 2 + 2 * LB;        // steady vmcnt: 3 newest half-tiles
  constexpr int AH = 256 * 32;          // elems per A half-region
  constexpr int BH = BN * 32;           // elems per B half-region

  int lin = blockIdx.x + gridDim.x * blockIdx.y;
  const int nblk = gridDim.x * gridDim.y;
  if ((nblk & 7) == 0)
    lin = (lin & 7) * (nblk >> 3) + (lin >> 3);   // XCD-contiguous remap
  const int bm = (lin / gridDim.x) * 256;
  const int bn = (lin % gridDim.x) * BN;
  A += (long)blockIdx.z * sA;
  B += (long)blockIdx.z * sB;

  const int tid = threadIdx.x;
  const int lane = tid & 63;
  const int wm = (tid >> 6) >> 2;       // 0..1
  const int wn = (tid >> 6) & 3;        // 0..3
  const int fm = lane & 15;
  const int fq = lane >> 4;

  __shared__ __align__(16) unsigned short Asm[2 * 2 * AH];
  __shared__ __align__(16) unsigned short Bsm[2 * 2 * BH];

  // staging source offsets (pre-swizzled global chunk; LDS dest is linear)
  long aoff[2];
#pragma unroll
  for (int i = 0; i < 2; ++i) {
    const int ci = i * 512 + tid;               // chunk 0..1023
    const int row = ci >> 2;
    const int g = (ci & 3) ^ ((row >> 1) & 3);
    aoff[i] = (long)(bm + row) * lda + g * 8;
  }
  long boff[LB];
#pragma unroll
  for (int i = 0; i < LB; ++i) {
    const int ci = i * 512 + tid;
    const int row = ci >> 2;
    const int g = (ci & 3) ^ ((row >> 1) & 3);
    boff[i] = (long)(bn + row) * ldb + g * 8;
  }

  const int NT = K >> 6;                        // 64-wide K-tiles

  auto stA = [&](int d, int kh, int t) {
    const unsigned short* s = A + t * 64 + kh * 32;
    unsigned short* dst = Asm + (d * 2 + kh) * AH;
#pragma unroll
    for (int i = 0; i < 2; ++i)
      gld_lds16(s + aoff[i], dst + (i * 512 + tid) * 8);
  };
  auto stB = [&](int d, int kh, int t) {
    const unsigned short* s = B + t * 64 + kh * 32;
    unsigned short* dst = Bsm + (d * 2 + kh) * BH;
#pragma unroll
    for (int i = 0; i < LB; ++i)
      gld_lds16(s + boff[i], dst + (i * 512 + tid) * 8);
  };

  // fragment read bases (slot is lane-constant since frag rows are 16-aligned)
  const int slotoff = (fq ^ ((fm >> 1) & 3)) * 8;
  const unsigned short* aRd = Asm + (wm * 128 + fm) * 32 + slotoff;
  const unsigned short* bRd = Bsm + (wn * (NF * 16) + fm) * 32 + slotoff;

  f32x4 acc[8][NF];
#pragma unroll
  for (int m = 0; m < 8; ++m)
#pragma unroll
    for (int n = 0; n < NF; ++n) acc[m][n] = (f32x4){0.f, 0.f, 0.f, 0.f};

  // prologue: tile0 fully + first 3 halves of tile1; wait leaves tile1's
  // 3 halves (= VM loads) in flight => tile0 landed.
  stB(0, 0, 0); stA(0, 0, 0); stB(0, 1, 0); stA(0, 1, 0);
  if (NT > 1) { stB(1, 0, 1); stA(1, 0, 1); stB(1, 1, 1); }
  SBAR();
  asm volatile("s_waitcnt vmcnt(%0)" :: "i"(VM) : "memory");
  __builtin_amdgcn_s_barrier();
  SBAR();

  bf16x8 af[4], bfr[NF];

  for (int t = 0; t < NT; ++t) {
    const int d = t & 1;
    const unsigned short* aB0 = aRd + d * (2 * AH);
    const unsigned short* bB0 = bRd + d * (2 * BH);
    const unsigned short* aB1 = aB0 + AH;
    const unsigned short* bB1 = bB0 + BH;

    // ---- phase 0: kh0 x m0-3 ----
#pragma unroll
    for (int m = 0; m < 4; ++m) af[m] = *(const bf16x8*)(aB0 + m * 512);
#pragma unroll
    for (int n = 0; n < NF; ++n) bfr[n] = *(const bf16x8*)(bB0 + n * 512);
    if (t + 1 < NT) stA(d ^ 1, 1, t + 1);
    FULLBAR();
    __builtin_amdgcn_s_setprio(1);
#pragma unroll
    for (int m = 0; m < 4; ++m)
#pragma unroll
      for (int n = 0; n < NF; ++n)
        acc[m][n] = __builtin_amdgcn_mfma_f32_16x16x32_bf16(af[m], bfr[n], acc[m][n], 0, 0, 0);
    __builtin_amdgcn_s_setprio(0);
    FULLBAR();

    // ---- phase 1: kh0 x m4-7 ----
#pragma unroll
    for (int m = 0; m < 4; ++m) af[m] = *(const bf16x8*)(aB0 + (4 + m) * 512);
    if (t + 2 < NT) stB(d, 0, t + 2);
    FULLBAR();
    __builtin_amdgcn_s_setprio(1);
#pragma unroll
    for (int m = 0; m < 4; ++m)
#pragma unroll
      for (int n = 0; n < NF; ++n)
        acc[4 + m][n] = __builtin_amdgcn_mfma_f32_16x16x32_bf16(af[m], bfr[n], acc[4 + m][n], 0, 0, 0);
    __builtin_amdgcn_s_setprio(0);
    FULLBAR();

    // ---- phase 2: kh1 x m0-3 ----
#pragma unroll
    for (int m = 0; m < 4; ++m) af[m] = *(const bf16x8*)(aB1 + m * 512);
#pragma unroll
    for (int n = 0; n < NF; ++n) bfr[n] = *(const bf16x8*)(bB1 + n * 512);
    if (t + 2 < NT) stA(d, 0, t + 2);
    FULLBAR();
    __builtin_amdgcn_s_setprio(1);
#pragma unroll
    for (int m = 0; m < 4; ++m)
#pragma unroll
      for (int n = 0; n < NF; ++n)
        acc[m][n] = __builtin_amdgcn_mfma_f32_16x16x32_bf16(af[m], bfr[n], acc[m][n], 0, 0, 0);
    __builtin_amdgcn_s_setprio(0);
    FULLBAR();

    // ---- phase 3: kh1 x m4-7 + counted boundary wait ----
#pragma unroll
    for (int m = 0; m < 4; ++m) af[m] = *(const bf16x8*)(aB1 + (4 + m) * 512);
    if (t + 2 < NT) stB(d, 1, t + 2);
    SBAR();
    if (t < NT - 2)
      asm volatile("s_waitcnt vmcnt(%0)" :: "i"(VM) : "memory");
    else
      asm volatile("s_waitcnt vmcnt(0)" ::: "memory");  // drain before last window
    __builtin_amdgcn_s_barrier();
    SBAR();
    __builtin_amdgcn_s_setprio(1);
#pragma unroll
    for (int m = 0; m < 4; ++m)
#pragma unroll
      for (int n = 0; n < NF; ++n)
        acc[4 + m][n] = __builtin_amdgcn_mfma_f32_16x16x32_bf16(af[m], bfr[n], acc[4 + m][n], 0, 0, 0);
    __builtin_amdgcn_s_setprio(0);
    FULLBAR();
  }

  // epilogue. (m,r) outer, n inner: two 32B halves of each 64B line written
  // back-to-back -> full-line writeback (R2 measured WRITE_SIZE at ideal).
  const long cb = (long)blockIdx.z * sC;
  float bv[NF];
#pragma unroll
  for (int n = 0; n < NF; ++n)
    bv[n] = bias ? bias[bn + wn * (NF * 16) + n * 16 + fm] : 0.f;
#pragma unroll
  for (int m = 0; m < 8; ++m) {
#pragma unroll
    for (int r = 0; r < 4; ++r) {
      const int row = bm + wm * 128 + m * 16 + fq * 4 + r;
#pragma unroll
      for (int n = 0; n < NF; ++n) {
        const int col = cColOff + bn + wn * (NF * 16) + n * 16 + fm;
        float v = acc[m][n][r] + bv[n];
        if (RELU) v = fmaxf(v, 0.f);
        if (OUT_BF16)
          ((unsigned short*)Cv)[cb + (long)row * ldc + col] = f2bf(v);
        else
          ((float*)Cv)[cb + (long)row * ldc + col] = v;
      }
    }
  }
}

// ---------------- bf16 NT GEMM, 16x16x32 MFMA, XOR-swizzled LDS -------------
// The workhorse 2-phase kernel (818 TF direct on QK).
// CAUSAL=0: plain rectangular grid.
// CAUSAL=1: lower-triangle compact grid (scores).
// CAUSAL=2: causal PV (O = P*Vt^T): per-block K = bm+128 (softmax zero-fills
//   P up to the 128-tile edge, so no masking needed). Block decode balances
//   per-XCD and per-CU load: XCD x gets qr=15-x (heavy, dispatched first)
//   + qr=x (light); every CU co-schedules heavy+light = uniform 34 K-iters.
//   8704 block-iters total vs 16896 in the old dual-64-row kernel.
template <int OUT_BF16, int RELU, int CAUSAL>
__global__ __launch_bounds__(256, 2) void k_gemm_nt(
    const unsigned short* __restrict__ A, const unsigned short* __restrict__ B,
    void* __restrict__ Cv, const float* __restrict__ bias,
    int M, int N, int K, int lda, int ldb, int ldc,
    long sA, long sB, long sC) {
  int bm, bn;
  int Keff = K;
  long cb;
  {
    int lin = blockIdx.x + gridDim.x * blockIdx.y;
    if (CAUSAL == 2) {
      // grid (8,64) = 512 blocks; lin = XCD-contiguous index
      const int l = (lin & 7) * 64 + (lin >> 3);
      const int x = l >> 6;            // XCD 0..7
      const int i = l & 63;
      const int half = i >> 5;         // 0 = heavy, 1 = light
      const int j = i & 31;
      const int qr = half ? x : 15 - x;
      const int zz = (j >> 3) & 3;
      const int dc = j & 7;
      bm = qr * 128;
      bn = dc * 128;
      Keff = bm + 128;
      A += (long)zz * sA;
      B += (long)zz * sB;
      cb = (long)zz * sC;
    } else {
      const int nblk = gridDim.x * gridDim.y;
      if ((nblk & 7) == 0)
        lin = (lin & 7) * (nblk >> 3) + (lin >> 3);
      if (CAUSAL == 1) {
        const int t = lin;
        int r = (int)floorf((sqrtf(8.f * (float)t + 1.f) - 1.f) * 0.5f);
        while ((r + 1) * (r + 2) / 2 <= t) ++r;
        while (r * (r + 1) / 2 > t) --r;
        bm = r * 128;
        bn = (t - r * (r + 1) / 2) * 128;
      } else {
        bm = (lin / gridDim.x) * 128;
        bn = (lin % gridDim.x) * 128;
      }
      A += (long)blockIdx.z * sA;
      B += (long)blockIdx.z * sB;
      cb = (long)blockIdx.z * sC;
    }
  }

  const int tid = threadIdx.x;
  const int lane = tid & 63;
  const int wm = ((tid >> 6) >> 1) * 64;
  const int wn = ((tid >> 6) & 1) * 64;

  __shared__ __align__(16) unsigned short Asm[128 * 64];
  __shared__ __align__(16) unsigned short Bsm[128 * 64];

  f32x4 acc[4][4];
#pragma unroll
  for (int i = 0; i < 4; ++i)
#pragma unroll
    for (int j = 0; j < 4; ++j) acc[i][j] = (f32x4){0.f, 0.f, 0.f, 0.f};

  const int r_row = tid >> 3;
  const int dst_k = (tid & 7) * 8;
  const int src_k = ((tid & 7) ^ ((tid >> 3) & 7)) * 8;
  const int fm = lane & 15;
  const int fq = lane >> 4;

  for (int k0 = 0; k0 < Keff; k0 += 64) {
#pragma unroll
    for (int i = 0; i < 4; ++i) {
      const int row = i * 32 + r_row;
      gld_lds16(A + (long)(bm + row) * lda + (k0 + src_k), Asm + row * 64 + dst_k);
      gld_lds16(B + (long)(bn + row) * ldb + (k0 + src_k), Bsm + row * 64 + dst_k);
    }
    __syncthreads();
#pragma unroll
    for (int kk = 0; kk < 2; ++kk) {
      bf16x8 af[4], bfr[4];
#pragma unroll
      for (int i = 0; i < 4; ++i) {
        const int pa = ((kk * 4 + fq) ^ (fm & 7)) * 8;
        af[i]  = *(const bf16x8*)(Asm + (wm + i * 16 + fm) * 64 + pa);
        bfr[i] = *(const bf16x8*)(Bsm + (wn + i * 16 + fm) * 64 + pa);
      }
#pragma unroll
      for (int i = 0; i < 4; ++i)
#pragma unroll
        for (int j = 0; j < 4; ++j)
          acc[i][j] = __builtin_amdgcn_mfma_f32_16x16x32_bf16(af[i], bfr[j], acc[i][j], 0, 0, 0);
    }
    __syncthreads();
  }

#pragma unroll
  for (int i = 0; i < 4; ++i) {
#pragma unroll
    for (int j = 0; j < 4; ++j) {
      const int col = bn + wn + j * 16 + fm;
      const float bv = bias ? bias[col] : 0.f;
#pragma unroll
      for (int r = 0; r < 4; ++r) {
        const int row = bm + wm + i * 16 + fq * 4 + r;
        float v = acc[i][j][r] + bv;
        if (RELU) v = fmaxf(v, 0.f);
        if (OUT_BF16)
          ((unsigned short*)Cv)[cb + (long)row * ldc + col] = f2bf(v);
        else
          ((float*)Cv)[cb + (long)row * ldc + col] = v;
      }
    }
  }
}

// ---------------- wave reductions ----------------
DI float wsum(float v) {
  v += __shfl_xor(v, 32, 64);
  v += __shfl_xor(v, 16, 64);
  v += __shfl_xor(v, 8, 64);
  v += __shfl_xor(v, 4, 64);
  v += __shfl_xor(v, 2, 64);
  v += __shfl_xor(v, 1, 64);
  return v;
}
DI float wmax(float v) {
  v = fmaxf(v, __shfl_xor(v, 32, 64));
  v = fmaxf(v, __shfl_xor(v, 16, 64));
  v = fmaxf(v, __shfl_xor(v, 8, 64));
  v = fmaxf(v, __shfl_xor(v, 4, 64));
  v = fmaxf(v, __shfl_xor(v, 2, 64));
  v = fmaxf(v, __shfl_xor(v, 1, 64));
  return v;
}

// ---------------- causal softmax: scores bf16 -> P bf16 ----------------
// Writes P for all k < lim = (q&~127)+128: real values k<=q, zeros above —
// the CAUSAL=2 PV GEMM relies on those zeros (its K-extent is exactly lim).
__global__ __launch_bounds__(256) void k_softmax_causal(
    const unsigned short* __restrict__ S, unsigned short* __restrict__ P) {
  const int row = blockIdx.x;           // 0..8191 flat (b*2048+q)
  const int q = row & (kS - 1);
  const int lim = (q & ~127) + 128;
  const unsigned short* Srow = S + (long)row * kS;
  unsigned short* Prow = P + (long)row * kS;
  const int tid = threadIdx.x;
  __shared__ float red[4];

  float v[8];
  float mx = -INFINITY;
#pragma unroll
  for (int i = 0; i < 8; ++i) {
    const int k = tid + i * 256;
    float xv = -INFINITY;
    if (k <= q) xv = bf2f(Srow[k]) * kScale;
    v[i] = xv;
    mx = fmaxf(mx, xv);
  }
  mx = wmax(mx);
  if ((tid & 63) == 0) red[tid >> 6] = mx;
  __syncthreads();
  mx = fmaxf(fmaxf(red[0], red[1]), fmaxf(red[2], red[3]));
  __syncthreads();

  float sum = 0.f;
#pragma unroll
  for (int i = 0; i < 8; ++i) {
    const float e = (v[i] > -INFINITY) ? __expf(v[i] - mx) : 0.f;
    v[i] = e;
    sum += e;
  }
  sum = wsum(sum);
  if ((tid & 63) == 0) red[tid >> 6] = sum;
  __syncthreads();
  sum = red[0] + red[1] + red[2] + red[3];
  const float inv = 1.f / sum;
#pragma unroll
  for (int i = 0; i < 8; ++i) {
    const int k = tid + i * 256;
    if (k < lim) Prow[k] = f2bf(v[i] * inv);
  }
}

// ------- fused residual + layernorm; X fp32 or bf16, out fp32 or bf16 -------
template <int X_BF16, int OUT_FP32>
__global__ __launch_bounds__(256) void k_residual_ln(
    const void* __restrict__ Xv, const unsigned short* __restrict__ Yb,
    const float* __restrict__ gamma, const float* __restrict__ beta,
    float* __restrict__ Out, unsigned short* __restrict__ OutB) {
  const long base = (long)blockIdx.x * kD;
  const int tid = threadIdx.x;
  __shared__ float reds[4], redss[4];
  float v[4];
  float s = 0.f, ss2 = 0.f;
#pragma unroll
  for (int i = 0; i < 4; ++i) {
    const int k = tid + i * 256;
    const float xf = X_BF16 ? bf2f(((const unsigned short*)Xv)[base + k])
                            : ((const float*)Xv)[base + k];
    const float xv = xf + bf2f(Yb[base + k]);
    v[i] = xv;
    s += xv;
    ss2 += xv * xv;
  }
  s = wsum(s);
  ss2 = wsum(ss2);
  if ((tid & 63) == 0) { reds[tid >> 6] = s; redss[tid >> 6] = ss2; }
  __syncthreads();
  s = reds[0] + reds[1] + reds[2] + reds[3];
  ss2 = redss[0] + redss[1] + redss[2] + redss[3];
  const float mu = s * (1.f / kD);
  float var = ss2 * (1.f / kD) - mu * mu;
  var = fmaxf(var, 0.f);
  const float rstd = rsqrtf(var + kEps);
#pragma unroll
  for (int i = 0; i < 4; ++i) {
    const int k = tid + i * 256;
    const float y = (v[i] - mu) * rstd * gamma[k] + beta[k];
    if (OUT_FP32) Out[base + k] = y;
    else          OutB[base + k] = f2bf(y);
  }
}

extern "C" void kernel_launch(void* const* d_in, const int* in_sizes, int n_in,
                              void* d_out, int out_size, void* d_ws, size_t ws_size,
                              hipStream_t stream) {
  (void)in_sizes; (void)n_in; (void)out_size; (void)ws_size;
  const float* x     = (const float*)d_in[0];
  const float* Wq    = (const float*)d_in[1];
  const float* Wk    = (const float*)d_in[2];
  const float* Wv    = (const float*)d_in[3];
  const float* W1    = (const float*)d_in[4];
  const float* b1    = (const float*)d_in[5];
  const float* W2    = (const float*)d_in[6];
  const float* b2    = (const float*)d_in[7];
  const float* gamma = (const float*)d_in[8];
  const float* beta  = (const float*)d_in[9];
  float* out = (float*)d_out;

  char* base = (char*)d_ws;
  size_t off = 0;
  auto alloc = [&](size_t bytes) -> void* {
    void* p = base + off;
    off = (off + bytes + 255) & ~(size_t)255;
    return p;
  };

  unsigned short* xb     = (unsigned short*)alloc((size_t)kM * kD * 2);       // 16 MB
  unsigned short* Wqkb   = (unsigned short*)alloc((size_t)2 * kD * kD * 2);   // 4 MB
  unsigned short* Wvb    = (unsigned short*)alloc((size_t)kD * kD * 2);       // 2 MB
  unsigned short* W1b    = (unsigned short*)alloc((size_t)kD * kD * 2);       // 2 MB
  unsigned short* W2b    = (unsigned short*)alloc((size_t)kD * kD * 2);       // 2 MB
  unsigned short* QKb    = (unsigned short*)alloc((size_t)kM * 2 * kD * 2);   // 32 MB
  unsigned short* Vt     = (unsigned short*)alloc((size_t)kM * kD * 2);       // 16 MB
  unsigned short* Sb     = (unsigned short*)alloc((size_t)kB * kS * kS * 2);  // 32 MB
  unsigned short* Pb     = (unsigned short*)alloc((size_t)kB * kS * kS * 2);  // 32 MB
  unsigned short* attn_b = (unsigned short*)alloc((size_t)kM * kD * 2);       // 16 MB
  unsigned short* ff_b = attn_b;             // attn dead after LN1
  unsigned short* hb   = Sb;                 // scores dead after softmax
  unsigned short* mid  = Pb;                 // P dead after attn GEMM

  dim3 blk(256);
  dim3 blk8(512);

  // fused casts
  {
    const int n4 = (kM * kD + 5 * kD * kD) / 4;
    k_cast_all<<<n4 / 256, blk, 0, stream>>>(x, Wq, Wk, Wv, W1, W2,
                                             xb, Wqkb, Wvb, W1b, W2b);
  }

  // QK projection: 2-phase 128^2 (818 TF direct).
  k_gemm_nt<1, 0, 0><<<dim3(2 * kD / 128, kM / 128, 1), blk, 0, stream>>>(
      xb, Wqkb, QKb, nullptr, kM, 2 * kD, kD, kD, kD, 2 * kD, 0, 0, 0);

  // Vt[b] = Wv x_b^T (8-phase NF=2, 256 blocks)
  k_gemm8p<2, 1, 0><<<dim3(kS / 128, kD / 256, kB), blk8, 0, stream>>>(
      Wvb, xb, Vt, nullptr, kD, kS, kD, kD, kD, kS,
      0, (long)kS * kD, (long)kD * kS, 0);

  // scores = Q K^T, lower-triangle compact grid
  k_gemm_nt<1, 0, 1><<<dim3(136, 1, kB), blk, 0, stream>>>(
      QKb, QKb + kD, Sb, nullptr, kS, kS, kD, 2 * kD, 2 * kD, kS,
      (long)kS * 2 * kD, (long)kS * 2 * kD, (long)kS * kS);

  // causal softmax -> P bf16 (zero-filled to each 128-tile edge)
  k_softmax_causal<<<kM, blk, 0, stream>>>(Sb, Pb);

  // attn = P Vt^T: causal-PV 128^2 tiles, per-block K = bm+128, balanced
  // heavy+light pairing per CU (replaces dual-64-row k_attn_pv; 0.52x iters).
  k_gemm_nt<1, 0, 2><<<dim3(8, 64, 1), blk, 0, stream>>>(
      Pb, Vt, attn_b, nullptr, kS, kD, 0, kS, kS, kD,
      (long)kS * kS, (long)kD * kS, (long)kS * kD);

  // h = LN(x + attn) -> bf16 only
  k_residual_ln<0, 0><<<kM, blk, 0, stream>>>(x, attn_b, gamma, beta,
                                              nullptr, hb);

  // FFN (8-phase NF=2, 256 blocks each)
  k_gemm8p<2, 1, 1><<<dim3(kD / 128, kM / 256, 1), blk8, 0, stream>>>(
      hb, W1b, mid, b1, kM, kD, kD, kD, kD, kD, 0, 0, 0, 0);
  k_gemm8p<2, 1, 0><<<dim3(kD / 128, kM / 256, 1), blk8, 0, stream>>>(
      mid, W2b, ff_b, b2, kM, kD, kD, kD, kD, kD, 0, 0, 0, 0);

  // out = LN(h + ff), h read as bf16
  k_residual_ln<1, 1><<<kM, blk, 0, stream>>>(hb, ff_b, gamma, beta,
                                              out, nullptr);
}

// Round 7
// 323.534 us; speedup vs baseline: 1.0490x; 1.0490x over previous
//
#include <hip/hip_runtime.h>
#include <math.h>
#include <cstdint>
#include <cstddef>

#define DI __device__ __forceinline__

typedef __bf16 bf16x8 __attribute__((ext_vector_type(8)));
typedef float f32x4 __attribute__((ext_vector_type(4)));
typedef unsigned short ushort8 __attribute__((ext_vector_type(8)));

static constexpr int kB = 4, kS = 2048, kD = 1024;
static constexpr int kM = kB * kS;            // 8192 tokens
static constexpr float kScale = 0.03125f;     // 1/sqrt(1024)
static constexpr float kEps = 1e-5f;

DI unsigned short f2bf(float f) {
  unsigned u = __float_as_uint(f);
  u += 0x7FFFu + ((u >> 16) & 1u);   // round-to-nearest-even
  return (unsigned short)(u >> 16);
}
DI float bf2f(unsigned short h) {
  return __uint_as_float(((unsigned)h) << 16);
}

DI void gld_lds16(const void* g, void* l) {
  __builtin_amdgcn_global_load_lds(
      (__attribute__((address_space(1))) void*)(void*)g,
      (__attribute__((address_space(3))) void*)l, 16, 0, 0);
}

#define SBAR() __builtin_amdgcn_sched_barrier(0)
#define FULLBAR() do { SBAR(); __builtin_amdgcn_s_barrier(); SBAR(); } while (0)

// ------- fused cast fp32 -> bf16 (x, Wq|Wk concat, Wv, W1, W2) -------
__global__ __launch_bounds__(256) void k_cast_all(
    const float* __restrict__ x, const float* __restrict__ Wq,
    const float* __restrict__ Wk, const float* __restrict__ Wv,
    const float* __restrict__ W1, const float* __restrict__ W2,
    unsigned short* __restrict__ xb, unsigned short* __restrict__ Wqkb,
    unsigned short* __restrict__ Wvb, unsigned short* __restrict__ W1b,
    unsigned short* __restrict__ W2b) {
  const int i = blockIdx.x * 256 + threadIdx.x;     // float4 index
  const int X4 = kM * kD / 4;                       // 2,097,152
  const int W4 = kD * kD / 4;                       // 262,144
  const float* src;
  unsigned short* dst;
  int j;
  if (i < X4) { src = x; dst = xb; j = i; }
  else if (i < X4 + W4)     { src = Wq; dst = Wqkb;          j = i - X4; }
  else if (i < X4 + 2 * W4) { src = Wk; dst = Wqkb + 4 * W4; j = i - X4 - W4; }
  else if (i < X4 + 3 * W4) { src = Wv; dst = Wvb;           j = i - X4 - 2 * W4; }
  else if (i < X4 + 4 * W4) { src = W1; dst = W1b;           j = i - X4 - 3 * W4; }
  else                      { src = W2; dst = W2b;           j = i - X4 - 4 * W4; }
  float4 v = ((const float4*)src)[j];
  ushort4 o;
  o.x = f2bf(v.x); o.y = f2bf(v.y); o.z = f2bf(v.z); o.w = f2bf(v.w);
  ((ushort4*)dst)[j] = o;
}

// ================= 8-phase 256-row bf16 NT GEMM (banked for Vt/FFN) =========
// Measured: modest win over 2-phase on the 256-block single-round shapes
// (R5 vs R0: -12us for the trio). LOST on QK in every config; never launch
// with != 256 blocks.
template <int NF, int OUT_BF16, int RELU>
__global__ __launch_bounds__(512, 2) void k_gemm8p(
    const unsigned short* __restrict__ A, const unsigned short* __restrict__ B,
    void* __restrict__ Cv, const float* __restrict__ bias,
    int M, int N, int K, int lda, int ldb, int ldc,
    long sA, long sB, long sC, int cColOff) {
  constexpr int BN = NF * 64;
  constexpr int LB = BN / 128;          // gld_lds issues per thread per B half
  constexpr int VM = 2 + 2 * LB;        // steady vmcnt: 3 newest half-tiles
  constexpr int AH = 256 * 32;          // elems per A half-region
  constexpr int BH = BN * 32;           // elems per B half-region

  int lin = blockIdx.x + gridDim.x * blockIdx.y;
  const int nblk = gridDim.x * gridDim.y;
  if ((nblk & 7) == 0)
    lin = (lin & 7) * (nblk >> 3) + (lin >> 3);   // XCD-contiguous remap
  const int bm = (lin / gridDim.x) * 256;
  const int bn = (lin % gridDim.x) * BN;
  A += (long)blockIdx.z * sA;
  B += (long)blockIdx.z * sB;

  const int tid = threadIdx.x;
  const int lane = tid & 63;
  const int wm = (tid >> 6) >> 2;       // 0..1
  const int wn = (tid >> 6) & 3;        // 0..3
  const int fm = lane & 15;
  const int fq = lane >> 4;

  __shared__ __align__(16) unsigned short Asm[2 * 2 * AH];
  __shared__ __align__(16) unsigned short Bsm[2 * 2 * BH];

  // staging source offsets (pre-swizzled global chunk; LDS dest is linear)
  long aoff[2];
#pragma unroll
  for (int i = 0; i < 2; ++i) {
    const int ci = i * 512 + tid;               // chunk 0..1023
    const int row = ci >> 2;
    const int g = (ci & 3) ^ ((row >> 1) & 3);
    aoff[i] = (long)(bm + row) * lda + g * 8;
  }
  long boff[LB];
#pragma unroll
  for (int i = 0; i < LB; ++i) {
    const int ci = i * 512 + tid;
    const int row = ci >> 2;
    const int g = (ci & 3) ^ ((row >> 1) & 3);
    boff[i] = (long)(bn + row) * ldb + g * 8;
  }

  const int NT = K >> 6;                        // 64-wide K-tiles

  auto stA = [&](int d, int kh, int t) {
    const unsigned short* s = A + t * 64 + kh * 32;
    unsigned short* dst = Asm + (d * 2 + kh) * AH;
#pragma unroll
    for (int i = 0; i < 2; ++i)
      gld_lds16(s + aoff[i], dst + (i * 512 + tid) * 8);
  };
  auto stB = [&](int d, int kh, int t) {
    const unsigned short* s = B + t * 64 + kh * 32;
    unsigned short* dst = Bsm + (d * 2 + kh) * BH;
#pragma unroll
    for (int i = 0; i < LB; ++i)
      gld_lds16(s + boff[i], dst + (i * 512 + tid) * 8);
  };

  // fragment read bases (slot is lane-constant since frag rows are 16-aligned)
  const int slotoff = (fq ^ ((fm >> 1) & 3)) * 8;
  const unsigned short* aRd = Asm + (wm * 128 + fm) * 32 + slotoff;
  const unsigned short* bRd = Bsm + (wn * (NF * 16) + fm) * 32 + slotoff;

  f32x4 acc[8][NF];
#pragma unroll
  for (int m = 0; m < 8; ++m)
#pragma unroll
    for (int n = 0; n < NF; ++n) acc[m][n] = (f32x4){0.f, 0.f, 0.f, 0.f};

  // prologue: tile0 fully + first 3 halves of tile1; wait leaves tile1's
  // 3 halves (= VM loads) in flight => tile0 landed.
  stB(0, 0, 0); stA(0, 0, 0); stB(0, 1, 0); stA(0, 1, 0);
  if (NT > 1) { stB(1, 0, 1); stA(1, 0, 1); stB(1, 1, 1); }
  SBAR();
  asm volatile("s_waitcnt vmcnt(%0)" :: "i"(VM) : "memory");
  __builtin_amdgcn_s_barrier();
  SBAR();

  bf16x8 af[4], bfr[NF];

  for (int t = 0; t < NT; ++t) {
    const int d = t & 1;
    const unsigned short* aB0 = aRd + d * (2 * AH);
    const unsigned short* bB0 = bRd + d * (2 * BH);
    const unsigned short* aB1 = aB0 + AH;
    const unsigned short* bB1 = bB0 + BH;

    // ---- phase 0: kh0 x m0-3 ----
#pragma unroll
    for (int m = 0; m < 4; ++m) af[m] = *(const bf16x8*)(aB0 + m * 512);
#pragma unroll
    for (int n = 0; n < NF; ++n) bfr[n] = *(const bf16x8*)(bB0 + n * 512);
    if (t + 1 < NT) stA(d ^ 1, 1, t + 1);
    FULLBAR();
    __builtin_amdgcn_s_setprio(1);
#pragma unroll
    for (int m = 0; m < 4; ++m)
#pragma unroll
      for (int n = 0; n < NF; ++n)
        acc[m][n] = __builtin_amdgcn_mfma_f32_16x16x32_bf16(af[m], bfr[n], acc[m][n], 0, 0, 0);
    __builtin_amdgcn_s_setprio(0);
    FULLBAR();

    // ---- phase 1: kh0 x m4-7 ----
#pragma unroll
    for (int m = 0; m < 4; ++m) af[m] = *(const bf16x8*)(aB0 + (4 + m) * 512);
    if (t + 2 < NT) stB(d, 0, t + 2);
    FULLBAR();
    __builtin_amdgcn_s_setprio(1);
#pragma unroll
    for (int m = 0; m < 4; ++m)
#pragma unroll
      for (int n = 0; n < NF; ++n)
        acc[4 + m][n] = __builtin_amdgcn_mfma_f32_16x16x32_bf16(af[m], bfr[n], acc[4 + m][n], 0, 0, 0);
    __builtin_amdgcn_s_setprio(0);
    FULLBAR();

    // ---- phase 2: kh1 x m0-3 ----
#pragma unroll
    for (int m = 0; m < 4; ++m) af[m] = *(const bf16x8*)(aB1 + m * 512);
#pragma unroll
    for (int n = 0; n < NF; ++n) bfr[n] = *(const bf16x8*)(bB1 + n * 512);
    if (t + 2 < NT) stA(d, 0, t + 2);
    FULLBAR();
    __builtin_amdgcn_s_setprio(1);
#pragma unroll
    for (int m = 0; m < 4; ++m)
#pragma unroll
      for (int n = 0; n < NF; ++n)
        acc[m][n] = __builtin_amdgcn_mfma_f32_16x16x32_bf16(af[m], bfr[n], acc[m][n], 0, 0, 0);
    __builtin_amdgcn_s_setprio(0);
    FULLBAR();

    // ---- phase 3: kh1 x m4-7 + counted boundary wait ----
#pragma unroll
    for (int m = 0; m < 4; ++m) af[m] = *(const bf16x8*)(aB1 + (4 + m) * 512);
    if (t + 2 < NT) stB(d, 1, t + 2);
    SBAR();
    if (t < NT - 2)
      asm volatile("s_waitcnt vmcnt(%0)" :: "i"(VM) : "memory");
    else
      asm volatile("s_waitcnt vmcnt(0)" ::: "memory");  // drain before last window
    __builtin_amdgcn_s_barrier();
    SBAR();
    __builtin_amdgcn_s_setprio(1);
#pragma unroll
    for (int m = 0; m < 4; ++m)
#pragma unroll
      for (int n = 0; n < NF; ++n)
        acc[4 + m][n] = __builtin_amdgcn_mfma_f32_16x16x32_bf16(af[m], bfr[n], acc[4 + m][n], 0, 0, 0);
    __builtin_amdgcn_s_setprio(0);
    FULLBAR();
  }

  // epilogue. (m,r) outer, n inner: two 32B halves of each 64B line written
  // back-to-back -> full-line writeback (R2 measured WRITE_SIZE at ideal).
  const long cb = (long)blockIdx.z * sC;
  float bv[NF];
#pragma unroll
  for (int n = 0; n < NF; ++n)
    bv[n] = bias ? bias[bn + wn * (NF * 16) + n * 16 + fm] : 0.f;
#pragma unroll
  for (int m = 0; m < 8; ++m) {
#pragma unroll
    for (int r = 0; r < 4; ++r) {
      const int row = bm + wm * 128 + m * 16 + fq * 4 + r;
#pragma unroll
      for (int n = 0; n < NF; ++n) {
        const int col = cColOff + bn + wn * (NF * 16) + n * 16 + fm;
        float v = acc[m][n][r] + bv[n];
        if (RELU) v = fmaxf(v, 0.f);
        if (OUT_BF16)
          ((unsigned short*)Cv)[cb + (long)row * ldc + col] = f2bf(v);
        else
          ((float*)Cv)[cb + (long)row * ldc + col] = v;
      }
    }
  }
}

// ---------------- bf16 NT GEMM, 16x16x32 MFMA, XOR-swizzled LDS -------------
// The workhorse 2-phase kernel (818 TF direct on QK). CAUSAL=0 rectangular,
// CAUSAL=1 lower-triangle compact grid (scores).
// R6 lesson: do NOT split causal PV into solo full-K blocks — losing the
// in-block dual-tile overlap costs ~2x per iter (MfmaUtil 35%->15%).
template <int OUT_BF16, int RELU, int CAUSAL>
__global__ __launch_bounds__(256, 2) void k_gemm_nt(
    const unsigned short* __restrict__ A, const unsigned short* __restrict__ B,
    void* __restrict__ Cv, const float* __restrict__ bias,
    int M, int N, int K, int lda, int ldb, int ldc,
    long sA, long sB, long sC) {
  int bm, bn;
  {
    int lin = blockIdx.x + gridDim.x * blockIdx.y;
    const int nblk = gridDim.x * gridDim.y;
    if ((nblk & 7) == 0)
      lin = (lin & 7) * (nblk >> 3) + (lin >> 3);
    if (CAUSAL == 1) {
      const int t = lin;
      int r = (int)floorf((sqrtf(8.f * (float)t + 1.f) - 1.f) * 0.5f);
      while ((r + 1) * (r + 2) / 2 <= t) ++r;
      while (r * (r + 1) / 2 > t) --r;
      bm = r * 128;
      bn = (t - r * (r + 1) / 2) * 128;
    } else {
      bm = (lin / gridDim.x) * 128;
      bn = (lin % gridDim.x) * 128;
    }
  }
  A += (long)blockIdx.z * sA;
  B += (long)blockIdx.z * sB;

  const int tid = threadIdx.x;
  const int lane = tid & 63;
  const int wm = ((tid >> 6) >> 1) * 64;
  const int wn = ((tid >> 6) & 1) * 64;

  __shared__ __align__(16) unsigned short Asm[128 * 64];
  __shared__ __align__(16) unsigned short Bsm[128 * 64];

  f32x4 acc[4][4];
#pragma unroll
  for (int i = 0; i < 4; ++i)
#pragma unroll
    for (int j = 0; j < 4; ++j) acc[i][j] = (f32x4){0.f, 0.f, 0.f, 0.f};

  const int r_row = tid >> 3;
  const int dst_k = (tid & 7) * 8;
  const int src_k = ((tid & 7) ^ ((tid >> 3) & 7)) * 8;
  const int fm = lane & 15;
  const int fq = lane >> 4;

  for (int k0 = 0; k0 < K; k0 += 64) {
#pragma unroll
    for (int i = 0; i < 4; ++i) {
      const int row = i * 32 + r_row;
      gld_lds16(A + (long)(bm + row) * lda + (k0 + src_k), Asm + row * 64 + dst_k);
      gld_lds16(B + (long)(bn + row) * ldb + (k0 + src_k), Bsm + row * 64 + dst_k);
    }
    __syncthreads();
#pragma unroll
    for (int kk = 0; kk < 2; ++kk) {
      bf16x8 af[4], bfr[4];
#pragma unroll
      for (int i = 0; i < 4; ++i) {
        const int pa = ((kk * 4 + fq) ^ (fm & 7)) * 8;
        af[i]  = *(const bf16x8*)(Asm + (wm + i * 16 + fm) * 64 + pa);
        bfr[i] = *(const bf16x8*)(Bsm + (wn + i * 16 + fm) * 64 + pa);
      }
#pragma unroll
      for (int i = 0; i < 4; ++i)
#pragma unroll
        for (int j = 0; j < 4; ++j)
          acc[i][j] = __builtin_amdgcn_mfma_f32_16x16x32_bf16(af[i], bfr[j], acc[i][j], 0, 0, 0);
    }
    __syncthreads();
  }

  const long cb = (long)blockIdx.z * sC;
#pragma unroll
  for (int i = 0; i < 4; ++i) {
#pragma unroll
    for (int j = 0; j < 4; ++j) {
      const int col = bn + wn + j * 16 + fm;
      const float bv = bias ? bias[col] : 0.f;
#pragma unroll
      for (int r = 0; r < 4; ++r) {
        const int row = bm + wm + i * 16 + fq * 4 + r;
        float v = acc[i][j][r] + bv;
        if (RELU) v = fmaxf(v, 0.f);
        if (OUT_BF16)
          ((unsigned short*)Cv)[cb + (long)row * ldc + col] = f2bf(v);
        else
          ((float*)Cv)[cb + (long)row * ldc + col] = v;
      }
    }
  }
}

// ------- balanced attn GEMM v3: O = P * Vt^T, 64-row dual tile -------------
// Restored from the 324.8us banked best (R6's full-K solo-block variant lost:
// dual tiles in ONE block keep stage/MFMA overlap alive for all 33 iters).
__global__ __launch_bounds__(256, 2) void k_attn_pv(
    const unsigned short* __restrict__ P, const unsigned short* __restrict__ Vt,
    unsigned short* __restrict__ O) {
  const int r = blockIdx.x;                       // 0..7
  const int q = blockIdx.y + 16 * blockIdx.z;     // 0..63
  const int lx = q & 7;                           // logical x (D col tile)
  const int pq = r + 8 * (q >> 3);                // group id 0..63
  const int pair = pq & 15;
  const int zz = pq >> 4;

  const int bn = lx * 128;
  const int bm_hi = (31 - pair) * 64;
  const int bm_lo = pair * 64;
  const int Khi = bm_hi + 64;
  const int Klo = bm_lo + 64;
  P  += (long)zz * kS * kS;
  Vt += (long)zz * kD * kS;
  O  += (long)zz * kS * kD;

  const int tid = threadIdx.x;
  const int lane = tid & 63;
  const int wn = (tid >> 6) * 32;

  __shared__ __align__(16) unsigned short Ah[64 * 64];
  __shared__ __align__(16) unsigned short Al[64 * 64];
  __shared__ __align__(16) unsigned short Bs[128 * 64];

  f32x4 ah[4][2], al[4][2];
#pragma unroll
  for (int i = 0; i < 4; ++i)
#pragma unroll
    for (int j = 0; j < 2; ++j) {
      ah[i][j] = (f32x4){0.f, 0.f, 0.f, 0.f};
      al[i][j] = (f32x4){0.f, 0.f, 0.f, 0.f};
    }

  const int r_row = tid >> 3;
  const int dst_k = (tid & 7) * 8;
  const int src_k = ((tid & 7) ^ ((tid >> 3) & 7)) * 8;
  const int fm = lane & 15;
  const int fq = lane >> 4;

  for (int k0 = 0; k0 < Khi; k0 += 64) {
    const bool lo = (k0 < Klo);
#pragma unroll
    for (int i = 0; i < 2; ++i) {
      const int row = i * 32 + r_row;
      gld_lds16(P + (long)(bm_hi + row) * kS + (k0 + src_k), Ah + row * 64 + dst_k);
      if (lo)
        gld_lds16(P + (long)(bm_lo + row) * kS + (k0 + src_k), Al + row * 64 + dst_k);
    }
#pragma unroll
    for (int i = 0; i < 4; ++i) {
      const int row = i * 32 + r_row;
      gld_lds16(Vt + (long)(bn + row) * kS + (k0 + src_k), Bs + row * 64 + dst_k);
    }
    __syncthreads();
#pragma unroll
    for (int kk = 0; kk < 2; ++kk) {
      bf16x8 afh[4], afl[4], bfr[2];
#pragma unroll
      for (int i = 0; i < 4; ++i) {
        const int ra = i * 16 + fm;
        const int pa = ((kk * 4 + fq) ^ (ra & 7)) * 8;
        afh[i] = *(const bf16x8*)(Ah + ra * 64 + pa);
        afl[i] = *(const bf16x8*)(Al + ra * 64 + pa);
      }
#pragma unroll
      for (int j = 0; j < 2; ++j) {
        const int rb = wn + j * 16 + fm;
        const int pb = ((kk * 4 + fq) ^ (rb & 7)) * 8;
        bfr[j] = *(const bf16x8*)(Bs + rb * 64 + pb);
      }
#pragma unroll
      for (int i = 0; i < 4; ++i)
#pragma unroll
        for (int j = 0; j < 2; ++j)
          ah[i][j] = __builtin_amdgcn_mfma_f32_16x16x32_bf16(afh[i], bfr[j], ah[i][j], 0, 0, 0);
      if (lo) {
#pragma unroll
        for (int i = 0; i < 4; ++i)
#pragma unroll
          for (int j = 0; j < 2; ++j)
            al[i][j] = __builtin_amdgcn_mfma_f32_16x16x32_bf16(afl[i], bfr[j], al[i][j], 0, 0, 0);
      }
    }
    __syncthreads();
  }

#pragma unroll
  for (int i = 0; i < 4; ++i) {
#pragma unroll
    for (int j = 0; j < 2; ++j) {
      const int col = bn + wn + j * 16 + fm;
#pragma unroll
      for (int r2 = 0; r2 < 4; ++r2) {
        const int rr = i * 16 + fq * 4 + r2;
        O[(long)(bm_hi + rr) * kD + col] = f2bf(ah[i][j][r2]);
        O[(long)(bm_lo + rr) * kD + col] = f2bf(al[i][j][r2]);
      }
    }
  }
}

// ---------------- wave reductions ----------------
DI float wsum(float v) {
  v += __shfl_xor(v, 32, 64);
  v += __shfl_xor(v, 16, 64);
  v += __shfl_xor(v, 8, 64);
  v += __shfl_xor(v, 4, 64);
  v += __shfl_xor(v, 2, 64);
  v += __shfl_xor(v, 1, 64);
  return v;
}
DI float wmax(float v) {
  v = fmaxf(v, __shfl_xor(v, 32, 64));
  v = fmaxf(v, __shfl_xor(v, 16, 64));
  v = fmaxf(v, __shfl_xor(v, 8, 64));
  v = fmaxf(v, __shfl_xor(v, 4, 64));
  v = fmaxf(v, __shfl_xor(v, 2, 64));
  v = fmaxf(v, __shfl_xor(v, 1, 64));
  return v;
}

// ---------------- causal softmax: scores bf16 -> P bf16 (vectorized) -------
// Each thread owns one contiguous ushort8 (16B load + 16B store) instead of
// 8 scalar u16 accesses (G13: hipcc never vectorizes scalar bf16).
// Tail beyond the causal edge is loaded but masked before use (workspace
// memory is always valid). lim is a multiple of 128 and k0 of 8, so the
// store predicate is uniform across the vector.
__global__ __launch_bounds__(256) void k_softmax_causal(
    const unsigned short* __restrict__ S, unsigned short* __restrict__ P) {
  const int row = blockIdx.x;           // 0..8191 flat (b*2048+q)
  const int q = row & (kS - 1);
  const int lim = (q & ~127) + 128;     // attn GEMM reads only k < lim
  const unsigned short* Srow = S + (long)row * kS;
  unsigned short* Prow = P + (long)row * kS;
  const int tid = threadIdx.x;
  const int k0 = tid * 8;
  __shared__ float red[4];

  const ushort8 s = *(const ushort8*)(Srow + k0);
  float v[8];
  float mx = -INFINITY;
#pragma unroll
  for (int j = 0; j < 8; ++j) {
    const float xv = (k0 + j <= q) ? bf2f(s[j]) * kScale : -INFINITY;
    v[j] = xv;
    mx = fmaxf(mx, xv);
  }
  mx = wmax(mx);
  if ((tid & 63) == 0) red[tid >> 6] = mx;
  __syncthreads();
  mx = fmaxf(fmaxf(red[0], red[1]), fmaxf(red[2], red[3]));
  __syncthreads();  // red reused below

  float sum = 0.f;
#pragma unroll
  for (int j = 0; j < 8; ++j) {
    const float e = (v[j] > -INFINITY) ? __expf(v[j] - mx) : 0.f;
    v[j] = e;
    sum += e;
  }
  sum = wsum(sum);
  if ((tid & 63) == 0) red[tid >> 6] = sum;
  __syncthreads();
  sum = red[0] + red[1] + red[2] + red[3];
  const float inv = 1.f / sum;
  if (k0 < lim) {
    ushort8 o;
#pragma unroll
    for (int j = 0; j < 8; ++j) o[j] = f2bf(v[j] * inv);
    *(ushort8*)(Prow + k0) = o;
  }
}

// ------- fused residual + layernorm; X fp32 or bf16, out fp32 or bf16 -------
template <int X_BF16, int OUT_FP32>
__global__ __launch_bounds__(256) void k_residual_ln(
    const void* __restrict__ Xv, const unsigned short* __restrict__ Yb,
    const float* __restrict__ gamma, const float* __restrict__ beta,
    float* __restrict__ Out, unsigned short* __restrict__ OutB) {
  const long base = (long)blockIdx.x * kD;
  const int tid = threadIdx.x;
  __shared__ float reds[4], redss[4];
  float v[4];
  float s = 0.f, ss2 = 0.f;
#pragma unroll
  for (int i = 0; i < 4; ++i) {
    const int k = tid + i * 256;
    const float xf = X_BF16 ? bf2f(((const unsigned short*)Xv)[base + k])
                            : ((const float*)Xv)[base + k];
    const float xv = xf + bf2f(Yb[base + k]);
    v[i] = xv;
    s += xv;
    ss2 += xv * xv;
  }
  s = wsum(s);
  ss2 = wsum(ss2);
  if ((tid & 63) == 0) { reds[tid >> 6] = s; redss[tid >> 6] = ss2; }
  __syncthreads();
  s = reds[0] + reds[1] + reds[2] + reds[3];
  ss2 = redss[0] + redss[1] + redss[2] + redss[3];
  const float mu = s * (1.f / kD);
  float var = ss2 * (1.f / kD) - mu * mu;
  var = fmaxf(var, 0.f);
  const float rstd = rsqrtf(var + kEps);
#pragma unroll
  for (int i = 0; i < 4; ++i) {
    const int k = tid + i * 256;
    const float y = (v[i] - mu) * rstd * gamma[k] + beta[k];
    if (OUT_FP32) Out[base + k] = y;
    else          OutB[base + k] = f2bf(y);
  }
}

extern "C" void kernel_launch(void* const* d_in, const int* in_sizes, int n_in,
                              void* d_out, int out_size, void* d_ws, size_t ws_size,
                              hipStream_t stream) {
  (void)in_sizes; (void)n_in; (void)out_size; (void)ws_size;
  const float* x     = (const float*)d_in[0];
  const float* Wq    = (const float*)d_in[1];
  const float* Wk    = (const float*)d_in[2];
  const float* Wv    = (const float*)d_in[3];
  const float* W1    = (const float*)d_in[4];
  const float* b1    = (const float*)d_in[5];
  const float* W2    = (const float*)d_in[6];
  const float* b2    = (const float*)d_in[7];
  const float* gamma = (const float*)d_in[8];
  const float* beta  = (const float*)d_in[9];
  float* out = (float*)d_out;

  char* base = (char*)d_ws;
  size_t off = 0;
  auto alloc = [&](size_t bytes) -> void* {
    void* p = base + off;
    off = (off + bytes + 255) & ~(size_t)255;
    return p;
  };

  unsigned short* xb     = (unsigned short*)alloc((size_t)kM * kD * 2);       // 16 MB
  unsigned short* Wqkb   = (unsigned short*)alloc((size_t)2 * kD * kD * 2);   // 4 MB
  unsigned short* Wvb    = (unsigned short*)alloc((size_t)kD * kD * 2);       // 2 MB
  unsigned short* W1b    = (unsigned short*)alloc((size_t)kD * kD * 2);       // 2 MB
  unsigned short* W2b    = (unsigned short*)alloc((size_t)kD * kD * 2);       // 2 MB
  unsigned short* QKb    = (unsigned short*)alloc((size_t)kM * 2 * kD * 2);   // 32 MB
  unsigned short* Vt     = (unsigned short*)alloc((size_t)kM * kD * 2);       // 16 MB
  unsigned short* Sb     = (unsigned short*)alloc((size_t)kB * kS * kS * 2);  // 32 MB
  unsigned short* Pb     = (unsigned short*)alloc((size_t)kB * kS * kS * 2);  // 32 MB
  unsigned short* attn_b = (unsigned short*)alloc((size_t)kM * kD * 2);       // 16 MB
  unsigned short* ff_b = attn_b;             // attn dead after LN1
  unsigned short* hb   = Sb;                 // scores dead after softmax
  unsigned short* mid  = Pb;                 // P dead after attn GEMM

  dim3 blk(256);
  dim3 blk8(512);

  // fused casts
  {
    const int n4 = (kM * kD + 5 * kD * kD) / 4;
    k_cast_all<<<n4 / 256, blk, 0, stream>>>(x, Wq, Wk, Wv, W1, W2,
                                             xb, Wqkb, Wvb, W1b, W2b);
  }

  // QK projection: 2-phase 128^2 (818 TF direct).
  k_gemm_nt<1, 0, 0><<<dim3(2 * kD / 128, kM / 128, 1), blk, 0, stream>>>(
      xb, Wqkb, QKb, nullptr, kM, 2 * kD, kD, kD, kD, 2 * kD, 0, 0, 0);

  // Vt[b] = Wv x_b^T (8-phase NF=2, 256 blocks)
  k_gemm8p<2, 1, 0><<<dim3(kS / 128, kD / 256, kB), blk8, 0, stream>>>(
      Wvb, xb, Vt, nullptr, kD, kS, kD, kD, kD, kS,
      0, (long)kS * kD, (long)kD * kS, 0);

  // scores = Q K^T, lower-triangle compact grid
  k_gemm_nt<1, 0, 1><<<dim3(136, 1, kB), blk, 0, stream>>>(
      QKb, QKb + kD, Sb, nullptr, kS, kS, kD, 2 * kD, 2 * kD, kS,
      (long)kS * 2 * kD, (long)kS * 2 * kD, (long)kS * kS);

  // causal softmax -> P bf16 (vectorized; writes only k < diagonal tile edge)
  k_softmax_causal<<<kM, blk, 0, stream>>>(Sb, Pb);

  // attn = P Vt^T, balanced 64-row dual-tile (restored banked-best version)
  k_attn_pv<<<dim3(8, 16, kB), blk, 0, stream>>>(Pb, Vt, attn_b);

  // h = LN(x + attn) -> bf16 only
  k_residual_ln<0, 0><<<kM, blk, 0, stream>>>(x, attn_b, gamma, beta,
                                              nullptr, hb);

  // FFN (8-phase NF=2, 256 blocks each)
  k_gemm8p<2, 1, 1><<<dim3(kD / 128, kM / 256, 1), blk8, 0, stream>>>(
      hb, W1b, mid, b1, kM, kD, kD, kD, kD, kD, 0, 0, 0, 0);
  k_gemm8p<2, 1, 0><<<dim3(kD / 128, kM / 256, 1), blk8, 0, stream>>>(
      mid, W2b, ff_b, b2, kM, kD, kD, kD, kD, kD, 0, 0, 0, 0);

  // out = LN(h + ff), h read as bf16
  k_residual_ln<1, 1><<<kM, blk, 0, stream>>>(hb, ff_b, gamma, beta,
                                              out, nullptr);
}